// Round 9
// baseline (262.791 us; speedup 1.0000x reference)
//
#include <hip/hip_runtime.h>
#include <hip/hip_bf16.h>
#include <math.h>

// ---------------------------------------------------------------------------
// MultiheadSelfAttentionWithRope on MI355X (gfx950), bf16 MFMA pipeline.
// B=4, S=2048, D=1024, H=16, dk=64.  fp32 accumulate everywhere.
//
// Stages:
//   1. convert x (+4 weights fused) fp32 -> bf16
//   2. trig table cos/sin [2048][32]
//   3. GEMM<0>: QKV projection (N=3072 fused); epilogue applies RoPE to Q,K
//      (Q also *0.125*log2e -> attn softmax runs in exp2 domain) and scatters
//      Q,K -> [b,h,s,dk]; V -> [b,h,dk,s] via LDS transpose
//   4. flash attention (swapped-QK^T, in-register exp2 softmax, defer-max)
//      -> ab [b,s,h,dk]
//   5. GEMM<1>: out = ab @ wo.T -> d_out fp32
//
// R4/R5 NaN post-mortem: raw-asm v_permlane32_swap_b32 was the only unproven
// primitive in both failing rounds (suspects: tied-operand register
// coalescing that "+&v" failed to prevent, or missing VALU->permlane
// wait-states that the compiler can't insert inside asm volatile). All
// cross-half exchanges are back on __shfl_xor(,32) — the R2-verified path.
// (R7/R8 were infra failures; this is the R6 bisection kernel, unchanged.)
// ---------------------------------------------------------------------------

typedef __bf16 bf16x8 __attribute__((ext_vector_type(8)));
typedef __bf16 bf16x4 __attribute__((ext_vector_type(4)));
typedef float  f32x4  __attribute__((ext_vector_type(4)));
typedef float  f32x16 __attribute__((ext_vector_type(16)));

#define GLB __attribute__((address_space(1)))
#define LDS __attribute__((address_space(3)))

__device__ __forceinline__ void gload_lds16(const void* g, void* l) {
  __builtin_amdgcn_global_load_lds((const GLB unsigned int*)g,
                                   (LDS unsigned int*)l, 16, 0, 0);
}

__device__ __forceinline__ unsigned pk2(float a, float b) {
  __bf16 x = (__bf16)a, y = (__bf16)b;
  unsigned short ux = __builtin_bit_cast(unsigned short, x);
  unsigned short uy = __builtin_bit_cast(unsigned short, y);
  return (unsigned)ux | ((unsigned)uy << 16);
}

// ---------------------------------------------------------------------------
__global__ __launch_bounds__(256) void conv_kernel(const float* __restrict__ in,
                                                   __bf16* __restrict__ out, int n4) {
  int i = blockIdx.x * 256 + threadIdx.x;
  if (i < n4) {
    float4 v = ((const float4*)in)[i];
    bf16x4 o = {(__bf16)v.x, (__bf16)v.y, (__bf16)v.z, (__bf16)v.w};
    ((bf16x4*)out)[i] = o;
  }
}

// 4 weight matrices (each 1M floats) in one launch
__global__ __launch_bounds__(256) void conv4_kernel(
    const float* __restrict__ a, const float* __restrict__ b,
    const float* __restrict__ c, const float* __restrict__ d,
    __bf16* __restrict__ oa, __bf16* __restrict__ ob,
    __bf16* __restrict__ oc, __bf16* __restrict__ od) {
  int i = blockIdx.x * 256 + threadIdx.x;  // 4 * 262144
  int w = i >> 18, j = i & 262143;
  const float* src = w == 0 ? a : (w == 1 ? b : (w == 2 ? c : d));
  __bf16* dst = w == 0 ? oa : (w == 1 ? ob : (w == 2 ? oc : od));
  float4 v = ((const float4*)src)[j];
  bf16x4 o = {(__bf16)v.x, (__bf16)v.y, (__bf16)v.z, (__bf16)v.w};
  ((bf16x4*)dst)[j] = o;
}

// ---------------------------------------------------------------------------
__global__ __launch_bounds__(256) void trig_kernel(const int* __restrict__ pos,
                                                   float2* __restrict__ trig) {
  int i = blockIdx.x * 256 + threadIdx.x;  // 65536 total
  int s = i >> 5, fi = i & 31;
  float p = (float)pos[s];
  float freq = expf(-(float)fi * 0.28782313662425574f);  // ln(10000)/32
  float ang = p * freq;
  trig[i] = make_float2(cosf(ang), sinf(ang));
}

// ---------------------------------------------------------------------------
// 2-phase double-buffered bf16 GEMM, 128x128 tile, BK=64, 4 waves.
// LDS tiles [128 rows][64 k], 16B-chunk XOR swizzle via pre-swizzled global src.
// Block map: mt = (bid&7)*8 + (idx&7), nt = idx>>3  (idx = bid>>3).
// MODE 0: N=3072 (wq|wk|wv); RoPE fused for Q,K; V transposed via LDS.
// MODE 1: N=1024 (wo), epilogue writes fp32 d_out.
// ---------------------------------------------------------------------------
template <int MODE>
__global__ __launch_bounds__(256, 2) void gemm_kernel(
    const __bf16* __restrict__ A, const __bf16* __restrict__ Bq,
    const __bf16* __restrict__ Bk, const __bf16* __restrict__ Bv,
    __bf16* __restrict__ Oq, __bf16* __restrict__ Ok, __bf16* __restrict__ Ov,
    float* __restrict__ Of, const float2* __restrict__ trig) {
  __shared__ unsigned char sm[65536];  // [A0 16K][B0 16K][A1 16K][B1 16K]
  int bid = blockIdx.x;
  int xcd = bid & 7, idx = bid >> 3;
  int mt = xcd * 8 + (idx & 7);   // XCD-local 8-tile A slab (2 MB, L2-resident)
  int nt = idx >> 3;
  int m0 = mt * 128;
  const __bf16* Bp;
  int ncol0, sel = 0;
  if (MODE == 0) {
    sel = nt >> 3;
    Bp = sel == 0 ? Bq : (sel == 1 ? Bk : Bv);
    ncol0 = (nt & 7) * 128;
  } else {
    Bp = Bq;
    ncol0 = nt * 128;
  }
  int t = threadIdx.x;
  int lane = t & 63, w = t >> 6;
  int g = lane >> 4, l15 = lane & 15;
  int wm = w >> 1, wn = w & 1;

  auto stage = [&](int buf, int kt) {
    unsigned boff = (unsigned)buf * 32768u;
#pragma unroll
    for (int l = 0; l < 4; ++l) {
      int c = t + l * 256;
      int r = c >> 3, sl = c & 7;
      int gk = kt * 64 + ((sl ^ (r & 7)) << 3);
      gload_lds16(A + (size_t)(m0 + r) * 1024 + gk, &sm[boff + (unsigned)c * 16]);
    }
#pragma unroll
    for (int l = 0; l < 4; ++l) {
      int c = t + l * 256;
      int r = c >> 3, sl = c & 7;
      int gk = kt * 64 + ((sl ^ (r & 7)) << 3);
      gload_lds16(Bp + (size_t)(ncol0 + r) * 1024 + gk,
                  &sm[boff + 16384u + (unsigned)c * 16]);
    }
  };

  f32x4 acc[4][4] = {};
  stage(0, 0);
  __syncthreads();
  int buf = 0;
  for (int kt = 0; kt < 16; ++kt) {
    if (kt + 1 < 16) stage(buf ^ 1, kt + 1);
    unsigned aoff = (unsigned)buf * 32768u, boff2 = aoff + 16384u;
#pragma unroll
    for (int ks = 0; ks < 2; ++ks) {
      bf16x8 aF[4], bF[4];
      int chunk = ks * 4 + g;
#pragma unroll
      for (int mi = 0; mi < 4; ++mi) {
        int r = wm * 64 + mi * 16 + l15;
        aF[mi] = *(const bf16x8*)&sm[aoff + (unsigned)(r * 128 + ((chunk ^ (r & 7)) << 4))];
      }
#pragma unroll
      for (int ni = 0; ni < 4; ++ni) {
        int r = wn * 64 + ni * 16 + l15;
        bF[ni] = *(const bf16x8*)&sm[boff2 + (unsigned)(r * 128 + ((chunk ^ (r & 7)) << 4))];
      }
#pragma unroll
      for (int mi = 0; mi < 4; ++mi)
#pragma unroll
        for (int ni = 0; ni < 4; ++ni)
          acc[mi][ni] = __builtin_amdgcn_mfma_f32_16x16x32_bf16(aF[mi], bF[ni],
                                                                acc[mi][ni], 0, 0, 0);
    }
    __syncthreads();
    buf ^= 1;
  }
  // ---- epilogue: C row = (lane>>4)*4+j, col = lane&15 ----
  if (MODE == 0 && sel == 2) {
    // V: transpose the 128x128 tile through LDS, store [b,h,d,s] coalesced.
#pragma unroll
    for (int mi = 0; mi < 4; ++mi)
#pragma unroll
      for (int ni = 0; ni < 4; ++ni)
#pragma unroll
        for (int j = 0; j < 4; ++j) {
          int row = wm * 64 + mi * 16 + g * 4 + j;
          int col = wn * 64 + ni * 16 + l15;
          unsigned byte = (unsigned)(col * 256 + ((((row >> 3) ^ (col & 15))) << 4) + ((row & 7) << 1));
          *(__bf16*)&sm[byte] = (__bf16)acc[mi][ni][j];
        }
    __syncthreads();
    int b = m0 >> 11, s0 = m0 & 2047;
#pragma unroll
    for (int i = 0; i < 8; ++i) {
      int c = t + i * 256;     // 0..2047
      int dcol = c >> 4;       // col_local 0..127
      int sc = c & 15;         // 8-s chunk
      bf16x8 v = *(const bf16x8*)&sm[(unsigned)(dcol * 256 + ((sc ^ (dcol & 15)) << 4))];
      int colg = ncol0 + dcol;
      int h = colg >> 6, d = colg & 63;
      *(bf16x8*)(Ov + (((size_t)(b * 16 + h)) * 64 + d) * 2048 + s0 + sc * 8) = v;
    }
  } else {
#pragma unroll
    for (int mi = 0; mi < 4; ++mi)
#pragma unroll
      for (int ni = 0; ni < 4; ++ni)
#pragma unroll
        for (int j = 0; j < 4; ++j) {
          int mg = m0 + wm * 64 + mi * 16 + g * 4 + j;
          int col = ncol0 + wn * 64 + ni * 16 + l15;
          float v = acc[mi][ni][j];
          if (MODE == 0) {
            int h = col >> 6, d = col & 63;
            int b = mg >> 11, s = mg & 2047;
            // fused RoPE: partner lane holds the other half of the (even,odd) pair
            float p = __shfl_xor(v, 1);
            float2 cs = trig[s * 32 + (d >> 1)];
            float o = (d & 1) ? (p * cs.y + v * cs.x) : (v * cs.x - p * cs.y);
            if (sel == 0) {
              o *= 0.18033688011112042f;  // (1/sqrt(dk)) * log2(e): exp2-domain softmax
              Oq[(((size_t)(b * 16 + h)) * 2048 + s) * 64 + d] = (__bf16)o;
            } else {
              Ok[(((size_t)(b * 16 + h)) * 2048 + s) * 64 + d] = (__bf16)o;
            }
          } else {
            Of[(size_t)mg * 1024 + col] = v;
          }
        }
  }
}

// ---------------------------------------------------------------------------
// Flash attention, causal, swapped-QK^T structure (32x32x16 MFMA).
// 4 waves x 32 q-rows -> q-tile 128; grid = 64 bh x 16 qt = 1024 blocks.
// bid map: bh = (bid&7)*8 + ((bid>>3)&7) keeps each XCD on 8 bh (KV in L2);
// qt = 15-(bid>>6), heavy first. KVBLK=64 double-buffered in LDS (K [64 kv]
// [64 d], V^T [64 d][64 kv], XOR-swizzled). mfma(K,Q): lane = one q-row;
// softmax in exp2 domain (scale pre-folded into Q), defer-max (THR=11.5 =
// 8*log2e). All cross-half traffic via __shfl_xor(,32) (R2-verified).
// ---------------------------------------------------------------------------
__global__ __launch_bounds__(256, 4) void attn_kernel(
    const __bf16* __restrict__ Q, const __bf16* __restrict__ Kb,
    const __bf16* __restrict__ Vt, __bf16* __restrict__ Ob) {
  __shared__ unsigned char sm[32768];  // [K0 8K][V0 8K][K1 8K][V1 8K]
  int bid = blockIdx.x;
  int bh = (bid & 7) * 8 + ((bid >> 3) & 7);
  int qt = 15 - (bid >> 6);
  int b = bh >> 4, h = bh & 15;
  const __bf16* Qp = Q + (size_t)bh * 2048 * 64;
  const __bf16* Kp = Kb + (size_t)bh * 2048 * 64;
  const __bf16* Vp = Vt + (size_t)bh * 64 * 2048;
  int t = threadIdx.x;
  int w = t >> 6, lane = t & 63;
  int q31 = lane & 31, hi = lane >> 5;
  int qw = qt * 128 + w * 32;
  int qg = qw + q31;

  // Q as B-operand fragments: k = kk*16 + hi*8 + idx
  bf16x8 qF[4];
#pragma unroll
  for (int kk = 0; kk < 4; ++kk)
    qF[kk] = *(const bf16x8*)(Qp + (size_t)qg * 64 + kk * 16 + hi * 8);

  f32x16 accO[2] = {};  // out^T: accO[dt][rr] -> d=(rr&3)+8*(rr>>2)+4*hi+32*dt, q=q31
  float m = -1e30f, l = 0.f;

  int nsteps = (qt + 1) * 2;
  auto stage = [&](int buf, int step) {
    int kv0 = step * 64;
#pragma unroll
    for (int i = 0; i < 2; ++i) {
      int c = t + i * 256;
      int r = c >> 3, sl = c & 7;
      gload_lds16(Kp + (size_t)(kv0 + r) * 64 + ((sl ^ (r & 7)) << 3),
                  &sm[(unsigned)buf * 16384u + (unsigned)c * 16]);
      gload_lds16(Vp + (size_t)r * 2048 + kv0 + ((sl ^ (r & 7)) << 3),
                  &sm[(unsigned)buf * 16384u + 8192u + (unsigned)c * 16]);
    }
  };

  stage(0, 0);
  __syncthreads();
  int buf = 0;
  for (int step = 0; step < nsteps; ++step) {
    if (step + 1 < nsteps) stage(buf ^ 1, step + 1);
    int kv0 = step * 64;
    if (kv0 <= qw) {  // wave-uniform causal skip (kv0, qw multiples of 32)
      unsigned koff = (unsigned)buf * 16384u, voff = koff + 8192u;
      f32x16 sc[2] = {};  // sc[tt][rr]: kv = kv0+32*tt+(rr&3)+8*(rr>>2)+4*hi, q=q31
      // ---- QK^T (swapped: A=K, B=Q) ----
      __builtin_amdgcn_s_setprio(1);
#pragma unroll
      for (int tt = 0; tt < 2; ++tt)
#pragma unroll
        for (int kk = 0; kk < 4; ++kk) {
          int row = tt * 32 + q31;
          int chunk = kk * 2 + hi;
          bf16x8 kf = *(const bf16x8*)&sm[koff + (unsigned)(row * 128 + ((chunk ^ (row & 7)) << 4))];
          sc[tt] = __builtin_amdgcn_mfma_f32_32x32x16_bf16(kf, qF[kk], sc[tt], 0, 0, 0);
        }
      __builtin_amdgcn_s_setprio(0);
      // ---- causal mask (only the diagonal-crossing step) ----
      if (kv0 + 64 > qw) {
        int hi4 = hi * 4;
#pragma unroll
        for (int tt = 0; tt < 2; ++tt)
#pragma unroll
          for (int rr = 0; rr < 16; ++rr) {
            int kvg = kv0 + tt * 32 + (rr & 3) + 8 * (rr >> 2) + hi4;
            if (kvg > qg) sc[tt][rr] = -1e30f;
          }
      }
      // ---- online softmax (exp2 domain), defer-max ----
      float pm = -1e30f;
#pragma unroll
      for (int tt = 0; tt < 2; ++tt)
#pragma unroll
        for (int rr = 0; rr < 16; ++rr) pm = fmaxf(pm, sc[tt][rr]);
      pm = fmaxf(pm, __shfl_xor(pm, 32));  // merge both halves of the q-row
      if (!__all(pm - m <= 11.5f)) {  // 11.5 = 8*log2(e): rescale only on growth
        float mnew = fmaxf(m, pm);
        float alpha = __builtin_exp2f(m - mnew);
        m = mnew;
        l *= alpha;
#pragma unroll
        for (int dt = 0; dt < 2; ++dt)
#pragma unroll
          for (int rr = 0; rr < 16; ++rr) accO[dt][rr] *= alpha;
      }
      float ls = 0.f;
#pragma unroll
      for (int tt = 0; tt < 2; ++tt)
#pragma unroll
        for (int rr = 0; rr < 16; ++rr) {
          float p = __builtin_exp2f(sc[tt][rr] - m);
          sc[tt][rr] = p;
          ls += p;
        }
      l += ls + __shfl_xor(ls, 32);
      // ---- P^T -> bf16 B-frags via shfl_xor(32) + PV (R2-verified) ----
#pragma unroll
      for (int tt = 0; tt < 2; ++tt) {
        unsigned pk[8];
#pragma unroll
        for (int i = 0; i < 8; ++i) pk[i] = pk2(sc[tt][2 * i], sc[tt][2 * i + 1]);
#pragma unroll
        for (int mm = 0; mm < 2; ++mm) {
          int ks = tt * 2 + mm;
          // exchange: hi=0 sends pk[4m+2..3], hi=1 sends pk[4m..4m+1]
          unsigned z0 = hi ? pk[4 * mm] : pk[4 * mm + 2];
          unsigned z1 = hi ? pk[4 * mm + 1] : pk[4 * mm + 3];
          unsigned zx0 = (unsigned)__shfl_xor((int)z0, 32);
          unsigned zx1 = (unsigned)__shfl_xor((int)z1, 32);
          union { unsigned u[4]; bf16x8 v; } pf;
          pf.u[0] = hi ? zx0 : pk[4 * mm];
          pf.u[1] = hi ? zx1 : pk[4 * mm + 1];
          pf.u[2] = hi ? pk[4 * mm + 2] : zx0;
          pf.u[3] = hi ? pk[4 * mm + 3] : zx1;
          __builtin_amdgcn_s_setprio(1);
#pragma unroll
          for (int dt = 0; dt < 2; ++dt) {
            int row = dt * 32 + q31;
            int chunk = ks * 2 + hi;
            bf16x8 vf = *(const bf16x8*)&sm[voff + (unsigned)(row * 128 + ((chunk ^ (row & 7)) << 4))];
            accO[dt] = __builtin_amdgcn_mfma_f32_32x32x16_bf16(vf, pf.v, accO[dt], 0, 0, 0);
          }
          __builtin_amdgcn_s_setprio(0);
        }
      }
    }
    __syncthreads();
    buf ^= 1;
  }
  // ---- epilogue: O = accO^T / l  ->  [b,s,h,d] bf16 ----
  float inv = 1.0f / l;
#pragma unroll
  for (int dt = 0; dt < 2; ++dt)
#pragma unroll
    for (int q4 = 0; q4 < 4; ++q4) {
      int dbase = dt * 32 + hi * 4 + 8 * q4;
      bf16x4 o;
#pragma unroll
      for (int ii = 0; ii < 4; ++ii) o[ii] = (__bf16)(accO[dt][q4 * 4 + ii] * inv);
      *(bf16x4*)(Ob + (((size_t)(b * 2048 + qg)) * 16 + h) * 64 + dbase) = o;
    }
}

// ---------------------------------------------------------------------------
extern "C" void kernel_launch(void* const* d_in, const int* in_sizes, int n_in,
                              void* d_out, int out_size, void* d_ws, size_t ws_size,
                              hipStream_t stream) {
  const float* x  = (const float*)d_in[0];
  const float* wq = (const float*)d_in[1];
  const float* wk = (const float*)d_in[2];
  const float* wv = (const float*)d_in[3];
  const float* wo = (const float*)d_in[4];
  const int* pos  = (const int*)d_in[5];
  float* out = (float*)d_out;

  char* ws = (char*)d_ws;
  size_t off = 0;
  auto alloc = [&](size_t bytes) {
    void* p = ws + off;
    off += (bytes + 255) & ~(size_t)255;
    return p;
  };
  __bf16* xb  = (__bf16*)alloc(16777216);   // [8192][1024]; dead after GEMM<0>
  __bf16* ab  = xb;                          // reuse: attn out [b,s,h,d]
  __bf16* wqb = (__bf16*)alloc(2097152);
  __bf16* wkb = (__bf16*)alloc(2097152);
  __bf16* wvb = (__bf16*)alloc(2097152);
  __bf16* wob = (__bf16*)alloc(2097152);
  __bf16* qb  = (__bf16*)alloc(16777216);   // [b,h,s,64] (rope'd, *0.125*log2e)
  __bf16* kb  = (__bf16*)alloc(16777216);   // [b,h,s,64] (rope'd)
  __bf16* vt  = (__bf16*)alloc(16777216);   // [b,h,64,s] (transposed)
  float2* trig = (float2*)alloc(524288);    // [2048][32]

  conv_kernel<<<8192, 256, 0, stream>>>(x, xb, 2097152);
  conv4_kernel<<<4096, 256, 0, stream>>>(wq, wk, wv, wo, wqb, wkb, wvb, wob);
  trig_kernel<<<256, 256, 0, stream>>>(pos, trig);

  gemm_kernel<0><<<1536, 256, 0, stream>>>(xb, wqb, wkb, wvb, qb, kb, vt, nullptr, trig);
  attn_kernel<<<1024, 256, 0, stream>>>(qb, kb, vt, ab);
  gemm_kernel<1><<<512, 256, 0, stream>>>(ab, wob, wob, wob, nullptr, nullptr, nullptr, out, nullptr);
}